// Round 12
// baseline (58.680 us; speedup 1.0000x reference)
//
#include <hip/hip_runtime.h>
#include <hip/hip_bf16.h>

#define NB 16384
#define ND 1024
#define NT 20
#define NC 100
#define NTILES_MAX 1044        // 16-row tiles: sum ceil(cnt_t/16) <= 1042
#define STEPS 16               // K steps of BK=64
#define ABUF 4096              // 16 rows x 64 f32 x 4B
#define BBUF 14336             // 14 fragment blocks x 1KB
#define BUFB (ABUF + BBUF)     // 18432; x4 = 73728 LDS -> 2 blocks/CU

typedef __bf16  bf16x8 __attribute__((ext_vector_type(8)));
typedef float   f32x4  __attribute__((ext_vector_type(4)));
typedef unsigned short ushort_t;

__device__ __forceinline__ unsigned int f2bf(float f) {
    unsigned int u = __builtin_bit_cast(unsigned int, f);
    u += 0x7FFFu + ((u >> 16) & 1u);   // RNE
    return u >> 16;
}
__device__ __forceinline__ unsigned long long pack4(float a, float b, float c, float d) {
    return (unsigned long long)f2bf(a)
         | ((unsigned long long)f2bf(b) << 16)
         | ((unsigned long long)f2bf(c) << 32)
         | ((unsigned long long)f2bf(d) << 48);
}
__device__ __forceinline__ bf16x8 mk_frag(float4 a, float4 b) {
    union { unsigned long long u[2]; bf16x8 v; } r;
    r.u[0] = pack4(a.x, a.y, a.z, a.w);
    r.u[1] = pack4(b.x, b.y, b.z, b.w);
    return r.v;
}

// async 16B/lane global->LDS; LDS dest = wave-uniform base + lane*16 (HW)
__device__ __forceinline__ void async_cp16(const void* g, void* l) {
    auto gp = reinterpret_cast<const __attribute__((address_space(1))) unsigned int*>(
        reinterpret_cast<unsigned long long>(g));
    auto lp = reinterpret_cast<__attribute__((address_space(3))) unsigned int*>(
        static_cast<unsigned int>(reinterpret_cast<unsigned long long>(l)));
    __builtin_amdgcn_global_load_lds(gp, lp, 16, 0, 0);
}

// ---------------- fused prep: wcvt (blocks 0..279) + bucket (block 280) -----
// R11-verified bodies; only the tile granularity changed (>>4).

__global__ __launch_bounds__(1024) void prep_kernel(
    const float* __restrict__ W, ushort_t* __restrict__ Wf,
    const int* __restrict__ t, int* __restrict__ offsets,
    int* __restrict__ tiles, int* __restrict__ idx_list)
{
    const int tid = threadIdx.x;
    if (blockIdx.x < 280) {
        int g = blockIdx.x * 1024 + tid;            // 286720 threads total
        int kg   = g & 127;
        int rest = g >> 7;
        int c    = rest % 112;
        int task = rest / 112;
        unsigned long long u0 = 0, u1 = 0;
        if (c < NC) {
            const float* p = W + ((size_t)(task * NC + c)) * ND + kg * 8;
            float4 a = *(const float4*)p;
            float4 b = *(const float4*)(p + 4);
            u0 = pack4(a.x, a.y, a.z, a.w);
            u1 = pack4(b.x, b.y, b.z, b.w);
        }
        size_t dst = (((size_t)task * 32 + (kg >> 2)) * 7 + (c >> 4)) * 512
                   + (size_t)((c & 15) | ((kg & 3) << 4)) * 8;
        *(unsigned long long*)(Wf + dst)     = u0;
        *(unsigned long long*)(Wf + dst + 4) = u1;
        return;
    }
    __shared__ int h[NT], off[NT + 1], cur[NT], tb[NT + 1];
    if (tid < NT) h[tid] = 0;
    __syncthreads();
    const int4* t4 = (const int4*)t;
    int4 v[4];
#pragma unroll
    for (int k = 0; k < 4; ++k) v[k] = t4[tid + k * 1024];
#pragma unroll
    for (int k = 0; k < 4; ++k) {
        atomicAdd(&h[v[k].x], 1); atomicAdd(&h[v[k].y], 1);
        atomicAdd(&h[v[k].z], 1); atomicAdd(&h[v[k].w], 1);
    }
    __syncthreads();
    if (tid == 0) {
        int acc = 0, tv = 0;
        for (int i = 0; i < NT; ++i) {
            off[i] = acc; cur[i] = acc; tb[i] = tv;
            acc += h[i]; tv += (h[i] + 15) >> 4;
        }
        off[NT] = acc; tb[NT] = tv;
    }
    __syncthreads();
    if (tid <= NT) offsets[tid] = off[tid];
    const int ntiles = tb[NT];
    for (int g = tid; g < NTILES_MAX; g += 1024) {
        int e = -1;
        if (g < ntiles) {
            int task = 0;
            while (tb[task + 1] <= g) ++task;
            e = (task << 16) | (g - tb[task]);
        }
        tiles[g] = e;
    }
#pragma unroll
    for (int k = 0; k < 4; ++k) {
        int base = (tid + k * 1024) * 4;
        idx_list[atomicAdd(&cur[v[k].x], 1)] = base;
        idx_list[atomicAdd(&cur[v[k].y], 1)] = base + 1;
        idx_list[atomicAdd(&cur[v[k].z], 1)] = base + 2;
        idx_list[atomicAdd(&cur[v[k].w], 1)] = base + 3;
    }
}

// ---------------- grouped GEMM: verified skeleton, depth-4 pipeline ---------
// Block = 16 rows x 112 cols x K=1024, 4 waves (wave w owns col-frags w, w+4).
// Per step: A 4x1KB async (inverse-swizzled f32 source) + B 14x1KB async
// (fragment-packed, linear) = 5 instrs/wave (2 dup B). 4 LDS buffers;
// STAGE(s+4) refills the buffer COMPUTE(s) drained -> 3 step-periods of
// latency slack. vmcnt(15) steady / 10,5,0 tail. Direct f32 store + bias.

__global__ __launch_bounds__(256, 2) void gemm_kernel(
    const float* __restrict__ x, const ushort_t* __restrict__ Wfrag,
    const float* __restrict__ bias, const int* __restrict__ offsets,
    const int* __restrict__ tiles, const int* __restrict__ idx_list,
    float* __restrict__ out)
{
    __shared__ __align__(16) char lds[4 * BUFB];
    const int ent = tiles[blockIdx.x];
    if (ent < 0) return;
    const int task = ent >> 16;
    const int m0   = (ent & 0xffff) << 4;
    const int seg  = offsets[task];
    const int cnt  = offsets[task + 1] - seg;

    const int tid  = threadIdx.x;
    const int wid  = tid >> 6;
    const int lane = tid & 63;
    const int csel = lane & 15;
    const int q    = lane >> 4;

    // A staging source: instr j = wid covers rows 4*wid..4*wid+3
    const float* srcA;
    {
        int row  = wid * 4 + q;
        int byte = csel * 16;
        int logb = byte ^ ((row & 7) << 4);     // inverse-swizzled source
        int sr   = m0 + row; if (sr > cnt - 1) sr = cnt - 1;
        srcA = x + (size_t)idx_list[seg + sr] * ND + (logb >> 2);
    }
    // B staging: fragment-packed, lane-linear; slots ii = kkb*7+frag
    const ushort_t* srcB = Wfrag + (size_t)task * (32 * 7 * 512) + lane * 8;
    int bii[4];
#pragma unroll
    for (int jj = 0; jj < 4; ++jj) {
        int i = wid + 4 * jj;
        bii[jj] = (i < 14) ? i : (i - 14);   // 2 dup stages: identical data, benign
    }

    auto STAGE = [&](int s, char* Ab) {
        char* Bb = Ab + ABUF;
        async_cp16(srcA + s * 64, Ab + wid * 1024);
#pragma unroll
        for (int jj = 0; jj < 4; ++jj)
            async_cp16(srcB + (size_t)(s * 14 + bii[jj]) * 512, Bb + bii[jj] * 1024);
    };

    const unsigned swzA = (unsigned)((csel & 7) << 4);
    const int f1ok = (wid + 4) < 7;          // wave 3 has only frag 3
    f32x4 acc[2] = {};

    auto COMPUTE = [&](const char* Ab) {
        const char* Bb = Ab + ABUF;
        const char* Ar = Ab + csel * 256;
#pragma unroll
        for (int kkb = 0; kkb < 2; ++kkb) {
            unsigned abase = (unsigned)(kkb * 128 + q * 32);
            float4 a0 = *(const float4*)(Ar + (abase ^ swzA));
            float4 a1 = *(const float4*)(Ar + ((abase + 16) ^ swzA));
            bf16x8 af = mk_frag(a0, a1);
            bf16x8 b0 = *(const bf16x8*)(Bb + (kkb * 7 + wid) * 1024 + lane * 16);
            acc[0] = __builtin_amdgcn_mfma_f32_16x16x32_bf16(af, b0, acc[0], 0, 0, 0);
            if (f1ok) {
                bf16x8 b1 = *(const bf16x8*)(Bb + (kkb * 7 + wid + 4) * 1024 + lane * 16);
                acc[1] = __builtin_amdgcn_mfma_f32_16x16x32_bf16(af, b1, acc[1], 0, 0, 0);
            }
        }
    };

    // prologue: 4 stages in flight (5 instrs x 4 per wave), wait stage 0
    STAGE(0, lds);
    STAGE(1, lds + BUFB);
    STAGE(2, lds + 2 * BUFB);
    STAGE(3, lds + 3 * BUFB);
    asm volatile("s_waitcnt vmcnt(15)" ::: "memory");   // my STAGE(0) landed
    __builtin_amdgcn_sched_barrier(0);
    __builtin_amdgcn_s_barrier();                       // everyone's STAGE(0) landed

#pragma unroll 1
    for (int s = 0; s < STEPS; ++s) {
        char* Ab = lds + (s & 3) * BUFB;
        COMPUTE(Ab);
        if (s == STEPS - 1) break;
        asm volatile("s_waitcnt lgkmcnt(0)" ::: "memory");   // my buf reads done
        __builtin_amdgcn_s_barrier();                        // all buf reads done
        if (s < STEPS - 4) {
            STAGE(s + 4, Ab);                                // refill drained buffer
            asm volatile("s_waitcnt vmcnt(15)" ::: "memory");// stage s+1 landed
        } else if (s == STEPS - 4) {
            asm volatile("s_waitcnt vmcnt(10)" ::: "memory");// stage s+1 landed
        } else if (s == STEPS - 3) {
            asm volatile("s_waitcnt vmcnt(5)" ::: "memory"); // stage s+1 landed
        } else {
            asm volatile("s_waitcnt vmcnt(0)" ::: "memory"); // stage s+1 landed
        }
        __builtin_amdgcn_sched_barrier(0);
        __builtin_amdgcn_s_barrier();
    }

    // epilogue: direct store + bias
    int oi[4];
#pragma unroll
    for (int rr = 0; rr < 4; ++rr) {
        int gm = m0 + q * 4 + rr;
        oi[rr] = (gm < cnt) ? idx_list[seg + gm] : -1;
    }
#pragma unroll
    for (int nf = 0; nf < 2; ++nf) {
        if (nf == 0 || f1ok) {
            int cg = (wid + nf * 4) * 16 + csel;
            if (cg < NC) {
                float bv = bias[task * NC + cg];
#pragma unroll
                for (int rr = 0; rr < 4; ++rr)
                    if (oi[rr] >= 0)
                        out[(size_t)oi[rr] * NC + cg] = acc[nf][rr] + bv;
            }
        }
    }
}

// ---------------- launch ----------------

extern "C" void kernel_launch(void* const* d_in, const int* in_sizes, int n_in,
                              void* d_out, int out_size, void* d_ws, size_t ws_size,
                              hipStream_t stream) {
    const float* x    = (const float*)d_in[0];
    const int*   t    = (const int*)d_in[1];
    const float* W    = (const float*)d_in[2];
    const float* bias = (const float*)d_in[3];

    char* ws = (char*)d_ws;
    int* offsets  = (int*)ws;                    // 21 ints  @ 0
    int* tiles    = (int*)(ws + 128);            // 1044 ints -> ends 4304
    int* idx_list = (int*)(ws + 4352);           // 16384 ints -> ends 69888
    ushort_t* Wf  = (ushort_t*)(ws + 69888);     // 4,587,520 B

    prep_kernel<<<281, 1024, 0, stream>>>(W, Wf, t, offsets, tiles, idx_list);
    gemm_kernel<<<NTILES_MAX, 256, 0, stream>>>(x, Wf, bias, offsets, tiles,
                                                idx_list, (float*)d_out);
}

// Round 13
// 47.409 us; speedup vs baseline: 1.2378x; 1.2378x over previous
//
#include <hip/hip_runtime.h>
#include <hip/hip_bf16.h>

#define NB 16384
#define ND 1024
#define NT 20
#define NC 100
#define NTILES_MAX 1044        // 16-row tiles: sum ceil(cnt_t/16) <= 1042

typedef __bf16  bf16x8 __attribute__((ext_vector_type(8)));
typedef float   f32x4  __attribute__((ext_vector_type(4)));
typedef unsigned short ushort_t;

__device__ __forceinline__ unsigned int f2bf(float f) {
    unsigned int u = __builtin_bit_cast(unsigned int, f);
    u += 0x7FFFu + ((u >> 16) & 1u);   // RNE
    return u >> 16;
}
__device__ __forceinline__ unsigned long long pack4(float a, float b, float c, float d) {
    return (unsigned long long)f2bf(a)
         | ((unsigned long long)f2bf(b) << 16)
         | ((unsigned long long)f2bf(c) << 32)
         | ((unsigned long long)f2bf(d) << 48);
}

// async 16B/lane global->LDS; LDS dest = wave-uniform base + lane*16 (HW)
__device__ __forceinline__ void async_cp16(const void* g, void* l) {
    auto gp = reinterpret_cast<const __attribute__((address_space(1))) unsigned int*>(
        reinterpret_cast<unsigned long long>(g));
    auto lp = reinterpret_cast<__attribute__((address_space(3))) unsigned int*>(
        static_cast<unsigned int>(reinterpret_cast<unsigned long long>(l)));
    __builtin_amdgcn_global_load_lds(gp, lp, 16, 0, 0);
}

// ---------------- fused prep: wcvt (blocks 0..279) + bucket (block 280) -----
// R12-verified verbatim.

__global__ __launch_bounds__(1024) void prep_kernel(
    const float* __restrict__ W, ushort_t* __restrict__ Wf,
    const int* __restrict__ t, int* __restrict__ offsets,
    int* __restrict__ tiles, int* __restrict__ idx_list)
{
    const int tid = threadIdx.x;
    if (blockIdx.x < 280) {
        int g = blockIdx.x * 1024 + tid;            // 286720 threads total
        int kg   = g & 127;
        int rest = g >> 7;
        int c    = rest % 112;
        int task = rest / 112;
        unsigned long long u0 = 0, u1 = 0;
        if (c < NC) {
            const float* p = W + ((size_t)(task * NC + c)) * ND + kg * 8;
            float4 a = *(const float4*)p;
            float4 b = *(const float4*)(p + 4);
            u0 = pack4(a.x, a.y, a.z, a.w);
            u1 = pack4(b.x, b.y, b.z, b.w);
        }
        size_t dst = (((size_t)task * 32 + (kg >> 2)) * 7 + (c >> 4)) * 512
                   + (size_t)((c & 15) | ((kg & 3) << 4)) * 8;
        *(unsigned long long*)(Wf + dst)     = u0;
        *(unsigned long long*)(Wf + dst + 4) = u1;
        return;
    }
    __shared__ int h[NT], off[NT + 1], cur[NT], tb[NT + 1];
    if (tid < NT) h[tid] = 0;
    __syncthreads();
    const int4* t4 = (const int4*)t;
    int4 v[4];
#pragma unroll
    for (int k = 0; k < 4; ++k) v[k] = t4[tid + k * 1024];
#pragma unroll
    for (int k = 0; k < 4; ++k) {
        atomicAdd(&h[v[k].x], 1); atomicAdd(&h[v[k].y], 1);
        atomicAdd(&h[v[k].z], 1); atomicAdd(&h[v[k].w], 1);
    }
    __syncthreads();
    if (tid == 0) {
        int acc = 0, tv = 0;
        for (int i = 0; i < NT; ++i) {
            off[i] = acc; cur[i] = acc; tb[i] = tv;
            acc += h[i]; tv += (h[i] + 15) >> 4;
        }
        off[NT] = acc; tb[NT] = tv;
    }
    __syncthreads();
    if (tid <= NT) offsets[tid] = off[tid];
    const int ntiles = tb[NT];
    for (int g = tid; g < NTILES_MAX; g += 1024) {
        int e = -1;
        if (g < ntiles) {
            int task = 0;
            while (tb[task + 1] <= g) ++task;
            e = (task << 16) | (g - tb[task]);
        }
        tiles[g] = e;
    }
#pragma unroll
    for (int k = 0; k < 4; ++k) {
        int base = (tid + k * 1024) * 4;
        idx_list[atomicAdd(&cur[v[k].x], 1)] = base;
        idx_list[atomicAdd(&cur[v[k].y], 1)] = base + 1;
        idx_list[atomicAdd(&cur[v[k].z], 1)] = base + 2;
        idx_list[atomicAdd(&cur[v[k].w], 1)] = base + 3;
    }
}

// ---------------- grouped GEMM: per-wave barrier-free B pipeline ------------
// Block = 16 rows x 112 cols x K=1024. Wave (kq,ch) = K-half x col-half
// (ch0: frags 0-3, ch1: frags 4-6). A: staged once to shared swizzled LDS
// (one barrier). B: per-wave PRIVATE 2x4KB double-buffer via global_load_lds
// from fragment-packed Wfrag; 16 steps BK=32, per-wave lgkmcnt(0) before each
// restage (the R8 bug fix), counted vmcnt, ZERO barriers in the K-loop.
// K-halves combined via LDS pub in fixed order; direct f32 store + bias.

__global__ __launch_bounds__(256, 2) void gemm_kernel(
    const float* __restrict__ x, const ushort_t* __restrict__ Wfrag,
    const float* __restrict__ bias, const int* __restrict__ offsets,
    const int* __restrict__ tiles, const int* __restrict__ idx_list,
    float* __restrict__ out)
{
    __shared__ __align__(16) char lds[65536];   // A: 0..32767, B: 32768 + wid*8192
    const int ent = tiles[blockIdx.x];
    if (ent < 0) return;
    const int task = ent >> 16;
    const int m0   = (ent & 0xffff) << 4;
    const int seg  = offsets[task];
    const int cnt  = offsets[task + 1] - seg;

    const int tid  = threadIdx.x;
    const int wid  = tid >> 6;
    const int lane = tid & 63;
    const int csel = lane & 15;
    const int q    = lane >> 4;
    const int kq   = wid >> 1;          // K-half
    const int ch   = wid & 1;           // col-half
    const int nf   = ch ? 3 : 4;        // fragments this wave owns
    const int fbase = ch ? 4 : 0;

    // epilogue row ids: loaded pre-pipeline, held in regs (fenced by asm below)
    int oi[4];
#pragma unroll
    for (int rr = 0; rr < 4; ++rr) {
        int gm = m0 + q * 4 + rr;
        oi[rr] = (gm < cnt) ? idx_list[seg + gm] : -1;
    }

    // ---- stage A: wave wid loads rows 4*wid..+3 contiguously, swizzled LDS ----
    const float* px[4];
#pragma unroll
    for (int j = 0; j < 4; ++j) {
        int mr = m0 + wid * 4 + j; if (mr > cnt - 1) mr = cnt - 1;
        px[j] = x + (size_t)idx_list[seg + mr] * ND + lane * 4;
    }
    float4 ar[16];
#pragma unroll
    for (int j = 0; j < 4; ++j)
#pragma unroll
        for (int qq = 0; qq < 4; ++qq)
            ar[j * 4 + qq] = *(const float4*)(px[j] + qq * 256);   // 1KB contiguous
#pragma unroll
    for (int j = 0; j < 4; ++j) {
        int rl = wid * 4 + j;
        unsigned swz = (unsigned)((rl & 7) << 4);
        char* base = lds + rl * 2048;
#pragma unroll
        for (int qq = 0; qq < 4; ++qq) {
            float4 v = ar[j * 4 + qq];
            *(unsigned long long*)(base + (((unsigned)(qq * 512 + lane * 8)) ^ swz)) =
                pack4(v.x, v.y, v.z, v.w);
        }
    }

    // ---- B per-wave private pipeline ----
    char* B0 = lds + 32768 + wid * 8192;
    char* B1 = B0 + 4096;
    const ushort_t* srcB = Wfrag + (size_t)task * (32 * 7 * 512) + lane * 8;

    auto BSTAGE = [&](int s, char* Bb) {
#pragma unroll
        for (int jj = 0; jj < 4; ++jj)
            if (jj < nf)
                async_cp16(srcB + (size_t)(((kq * 16 + s) * 7) + fbase + jj) * 512,
                           Bb + jj * 1024);
    };

    asm volatile("s_waitcnt vmcnt(0)" ::: "memory");     // zero the vmcnt baseline
    BSTAGE(0, B0);
    BSTAGE(1, B1);
    asm volatile("s_waitcnt lgkmcnt(0)" ::: "memory");   // my A ds_writes done
    __builtin_amdgcn_s_barrier();                        // A visible block-wide

    const char* Arow = lds + csel * 2048;
    const unsigned aswz = (unsigned)((csel & 7) << 4);
    const unsigned akq  = (unsigned)(kq * 1024 + q * 16);
    f32x4 acc[4] = {};

    if (ch == 0) asm volatile("s_waitcnt vmcnt(4)" ::: "memory");   // stage 0 landed
    else         asm volatile("s_waitcnt vmcnt(3)" ::: "memory");
    __builtin_amdgcn_sched_barrier(0);

#pragma unroll 1
    for (int s = 0; s < 16; ++s) {
        const char* Bb = (s & 1) ? B1 : B0;
        bf16x8 af = *(const bf16x8*)(Arow + ((akq + (unsigned)(s * 64)) ^ aswz));
#pragma unroll
        for (int jj = 0; jj < 4; ++jj) {
            if (jj < nf) {
                bf16x8 bf = *(const bf16x8*)(Bb + jj * 1024 + lane * 16);
                acc[jj] = __builtin_amdgcn_mfma_f32_16x16x32_bf16(af, bf, acc[jj], 0, 0, 0);
            }
        }
        if (s == 15) break;
        asm volatile("s_waitcnt lgkmcnt(0)" ::: "memory");   // my reads of Bb done
        if (s < 14) {
            BSTAGE(s + 2, (s & 1) ? B1 : B0);                // refill just-read buffer
            if (ch == 0) asm volatile("s_waitcnt vmcnt(4)" ::: "memory");  // s+1 landed
            else         asm volatile("s_waitcnt vmcnt(3)" ::: "memory");
        } else {
            asm volatile("s_waitcnt vmcnt(0)" ::: "memory"); // last stage landed
        }
        __builtin_amdgcn_sched_barrier(0);
    }

    // ---- combine K-halves (fixed order => deterministic), store ----
    __syncthreads();                      // all waves done reading A/B
    float* pub = (float*)lds;             // [2 ch][64 lanes][17] over A region
    if (kq == 1) {
#pragma unroll
        for (int jj = 0; jj < 4; ++jj)
#pragma unroll
            for (int rr = 0; rr < 4; ++rr)
                pub[(ch * 64 + lane) * 17 + jj * 4 + rr] = acc[jj][rr];
    }
    __syncthreads();
    if (kq == 0) {
#pragma unroll
        for (int jj = 0; jj < 4; ++jj) {
            if (jj < nf) {
                int cg = (fbase + jj) * 16 + csel;
                if (cg < NC) {
                    float bv = bias[task * NC + cg];
#pragma unroll
                    for (int rr = 0; rr < 4; ++rr) {
                        float v = acc[jj][rr] + pub[(ch * 64 + lane) * 17 + jj * 4 + rr];
                        if (oi[rr] >= 0)
                            out[(size_t)oi[rr] * NC + cg] = v + bv;
                    }
                }
            }
        }
    }
}

// ---------------- launch ----------------

extern "C" void kernel_launch(void* const* d_in, const int* in_sizes, int n_in,
                              void* d_out, int out_size, void* d_ws, size_t ws_size,
                              hipStream_t stream) {
    const float* x    = (const float*)d_in[0];
    const int*   t    = (const int*)d_in[1];
    const float* W    = (const float*)d_in[2];
    const float* bias = (const float*)d_in[3];

    char* ws = (char*)d_ws;
    int* offsets  = (int*)ws;                    // 21 ints  @ 0
    int* tiles    = (int*)(ws + 128);            // 1044 ints -> ends 4304
    int* idx_list = (int*)(ws + 4352);           // 16384 ints -> ends 69888
    ushort_t* Wf  = (ushort_t*)(ws + 69888);     // 4,587,520 B

    prep_kernel<<<281, 1024, 0, stream>>>(W, Wf, t, offsets, tiles, idx_list);
    gemm_kernel<<<NTILES_MAX, 256, 0, stream>>>(x, Wf, bias, offsets, tiles,
                                                idx_list, (float*)d_out);
}